// Round 10
// baseline (105.520 us; speedup 1.0000x reference)
//
#include <hip/hip_runtime.h>

#define BN_EPS 1e-5f
#define NEG_SLOPE 0.2f

constexpr int B_ = 16384;
constexpr int Din = 4096;
constexpr int Dout = 256;
constexpr int D_RANK = 20;
constexpr int NMVBLK = 1024;   // matvec grid; 16 rows/block; one partial each

typedef float f4 __attribute__((ext_vector_type(4)));

// ws layout (floats):
// [0, 16384)       : t
// [16384, ...)     : partials: 1024 x double2 (byte 65536, 16B-aligned)
#define WS_T 0
#define WS_PART 16384

// ---------------- Kernel 1: Bv synth (in-block) + t = x @ Bv + partial -------
// 512 threads = 8 waves; 16 rows/block (2 rows/wave, interleaved); grid 1024
// = 4 blocks/CU = 32 waves/CU. Bv is synthesized redundantly per block into
// LDS from cB (320 KB, L2-hot after first touch): kills the dependent k_synth
// launch. No fence/atomic anywhere (round 8: device-scope sync in streaming
// kernels = 3x). x is the only sustained VMEM stream.
__global__ __launch_bounds__(512) void k_mv(
    const float* __restrict__ x, const float* __restrict__ alphas,
    const float* __restrict__ cB, float* __restrict__ t,
    double2* __restrict__ partials) {
  __shared__ f4 bvs[Din / 4];   // 16 KiB
  __shared__ float al[D_RANK];
  __shared__ float tv[16];
  int tid = threadIdx.x;
  if (tid < D_RANK) al[tid] = alphas[tid];
  __syncthreads();

  // Bv[8t .. 8t+7]: 640 contiguous bytes of cB per thread, adjacent threads
  // adjacent regions (coalesced, L2-hot).
  {
    const float* cb = cB + (size_t)tid * 8 * D_RANK;
    float v[8];
#pragma unroll
    for (int i = 0; i < 8; ++i) {
      float s = 0.f;
#pragma unroll
      for (int d = 0; d < D_RANK; ++d) s += al[d] * cb[i * D_RANK + d];
      v[i] = s;
    }
    f4 lo, hi;
    lo.x = v[0]; lo.y = v[1]; lo.z = v[2]; lo.w = v[3];
    hi.x = v[4]; hi.y = v[5]; hi.z = v[6]; hi.w = v[7];
    bvs[tid * 2] = lo;
    bvs[tid * 2 + 1] = hi;
  }
  __syncthreads();

  int wave = tid >> 6;   // 0..7
  int lane = tid & 63;
  int r0 = blockIdx.x * 16 + wave * 2;
  const f4* x0 = reinterpret_cast<const f4*>(x + (size_t)r0 * Din);
  const f4* x1 = reinterpret_cast<const f4*>(x + (size_t)(r0 + 1) * Din);
  float a00 = 0.f, a01 = 0.f, a10 = 0.f, a11 = 0.f;
#pragma unroll
  for (int it = 0; it < 8; ++it) {
    f4 xa0 = x0[it * 128 + lane];
    f4 xb0 = x0[it * 128 + 64 + lane];
    f4 xa1 = x1[it * 128 + lane];
    f4 xb1 = x1[it * 128 + 64 + lane];
    f4 ba = bvs[it * 128 + lane];
    f4 bb = bvs[it * 128 + 64 + lane];
    a00 += xa0.x * ba.x + xa0.y * ba.y + xa0.z * ba.z + xa0.w * ba.w;
    a01 += xb0.x * bb.x + xb0.y * bb.y + xb0.z * bb.z + xb0.w * bb.w;
    a10 += xa1.x * ba.x + xa1.y * ba.y + xa1.z * ba.z + xa1.w * ba.w;
    a11 += xb1.x * bb.x + xb1.y * bb.y + xb1.z * bb.z + xb1.w * bb.w;
  }
  float s0 = a00 + a01;
  float s1 = a10 + a11;
#pragma unroll
  for (int off = 32; off > 0; off >>= 1) {
    s0 += __shfl_down(s0, off, 64);
    s1 += __shfl_down(s1, off, 64);
  }
  if (lane == 0) {
    t[r0] = s0;
    t[r0 + 1] = s1;
    tv[wave * 2] = s0;
    tv[wave * 2 + 1] = s1;
  }
  __syncthreads();
  if (tid == 0) {
    double s = 0.0, q = 0.0;
#pragma unroll
    for (int w = 0; w < 16; ++w) {
      double v = (double)tv[w];
      s += v;
      q += v * v;
    }
    partials[blockIdx.x] = make_double2(s, q);
  }
}

// ---------------- Kernel 2: stats (redundant per block) + BN + leaky + write -
// 1024 blocks x 1024 threads, 16 rows each. Each block reduces all 1024
// partials in fixed index order (deterministic; 16 KB, L2-hot; 16 MB
// aggregate), synthesizes A from cA (20 KB, L2-hot), then streams its 16
// output rows. One f4 store per thread.
__global__ __launch_bounds__(1024) void k_fin(
    const float* __restrict__ t, const double2* __restrict__ partials,
    const float* __restrict__ alphas, const float* __restrict__ cA,
    const float* __restrict__ gamma, const float* __restrict__ beta,
    float* __restrict__ out) {
  __shared__ double sd[1024];   // 8 KiB
  __shared__ double sq[1024];   // 8 KiB
  __shared__ float ss[Dout];
  __shared__ float bs[Dout];
  __shared__ float ts[16];
  __shared__ float al[D_RANK];
  int tid = threadIdx.x;
  double2 p = partials[tid];
  if (tid < D_RANK) al[tid] = alphas[tid];
  if (tid < 16) ts[tid] = t[blockIdx.x * 16 + tid];
  sd[tid] = p.x;
  sq[tid] = p.y;
  __syncthreads();
  for (int off = 512; off > 0; off >>= 1) {
    if (tid < off) {
      sd[tid] += sd[tid + off];
      sq[tid] += sq[tid + off];
    }
    __syncthreads();
  }
  double mean = sd[0] / (double)B_;
  double var = sq[0] / (double)B_ - mean * mean;  // biased, matches jnp.var
  if (tid < Dout) {
    float a = 0.f;
#pragma unroll
    for (int d = 0; d < D_RANK; ++d) a += al[d] * cA[d * Dout + tid];
    float inv = rsqrtf((float)((double)a * (double)a * var) + BN_EPS);
    float sj = a * gamma[tid] * inv;
    ss[tid] = sj;
    bs[tid] = beta[tid] - (float)mean * sj;
  }
  __syncthreads();
  int rin = tid >> 6;    // 0..15
  int c4 = tid & 63;     // 64 f4 per 256-col row
  int row = blockIdx.x * 16 + rin;
  float tvv = ts[rin];
  f4 sv = *reinterpret_cast<const f4*>(&ss[c4 * 4]);
  f4 bv = *reinterpret_cast<const f4*>(&bs[c4 * 4]);
  f4 o;
  o.x = tvv * sv.x + bv.x; o.x = (o.x >= 0.f) ? o.x : NEG_SLOPE * o.x;
  o.y = tvv * sv.y + bv.y; o.y = (o.y >= 0.f) ? o.y : NEG_SLOPE * o.y;
  o.z = tvv * sv.z + bv.z; o.z = (o.z >= 0.f) ? o.z : NEG_SLOPE * o.z;
  o.w = tvv * sv.w + bv.w; o.w = (o.w >= 0.f) ? o.w : NEG_SLOPE * o.w;
  reinterpret_cast<f4*>(out)[(size_t)row * (Dout / 4) + c4] = o;
}

extern "C" void kernel_launch(void* const* d_in, const int* in_sizes, int n_in,
                              void* d_out, int out_size, void* d_ws, size_t ws_size,
                              hipStream_t stream) {
  const float* x      = (const float*)d_in[0];
  const float* alphas = (const float*)d_in[1];
  const float* cA     = (const float*)d_in[2];
  const float* cB     = (const float*)d_in[3];
  // d_in[4] = linear_bias: cancels exactly inside BatchNorm (out - mean).
  const float* gamma  = (const float*)d_in[5];
  const float* beta   = (const float*)d_in[6];
  float* out = (float*)d_out;
  float* ws  = (float*)d_ws;

  float*   t        = ws + WS_T;
  double2* partials = reinterpret_cast<double2*>(ws + WS_PART);

  k_mv<<<NMVBLK, 512, 0, stream>>>(x, alphas, cB, t, partials);
  k_fin<<<B_ / 16, 1024, 0, stream>>>(t, partials, alphas, cA, gamma, beta, out);
}

// Round 11
// 56.079 us; speedup vs baseline: 1.8816x; 1.8816x over previous
//
#include <hip/hip_runtime.h>

#define BN_EPS 1e-5f
#define NEG_SLOPE 0.2f

constexpr int B_ = 16384;
constexpr int Din = 4096;
constexpr int Dout = 256;
constexpr int D_RANK = 20;
constexpr int NPART = 2048;   // one partial per matvec block

typedef float f4 __attribute__((ext_vector_type(4)));

// ws layout (floats):
// [0, 4096)        : Bv
// [4096, 4352)     : A
// [4352, 20736)    : t (16384)
// [20736, 28928)   : partials: 2048 x double2 (byte 82944, 16B-aligned)
#define WS_BV 0
#define WS_A 4096
#define WS_T 4352
#define WS_PART 20736

// ---------------- Kernel 1: synthesize A (Dout) and Bv (Din) -----------------
__global__ __launch_bounds__(256) void k_synth(
    const float* __restrict__ alphas, const float* __restrict__ cA,
    const float* __restrict__ cB, float* __restrict__ A, float* __restrict__ Bv) {
  __shared__ float al[D_RANK];
  int tid = threadIdx.x;
  if (tid < D_RANK) al[tid] = alphas[tid];
  __syncthreads();
  if (blockIdx.x == 0) {
    float s = 0.f;
#pragma unroll
    for (int d = 0; d < D_RANK; ++d) s += al[d] * cA[d * Dout + tid];
    A[tid] = s;
  } else {
    int k = (blockIdx.x - 1) * 256 + tid;
    float s = 0.f;
#pragma unroll
    for (int d = 0; d < D_RANK; ++d) s += al[d] * cB[k * D_RANK + d];
    Bv[k] = s;
  }
}

// ---------------- Kernel 2: t = x @ Bv + per-block (sum, sumsq) partial ------
// PROVEN round-7/9 kernel, untouched: 512 threads = 8 waves, one row/wave,
// grid 2048. Bv staged in LDS so x is the only VMEM stream. No fence/atomic
// (round 8: device-scope sync in streaming kernels = 3x slowdown).
__global__ __launch_bounds__(512) void k_matvec(
    const float* __restrict__ x, const float* __restrict__ Bv,
    float* __restrict__ t, double2* __restrict__ partials) {
  __shared__ f4 bvs[Din / 4];   // 16 KiB
  int tid = threadIdx.x;
  const f4* bv = reinterpret_cast<const f4*>(Bv);
  bvs[tid] = bv[tid];
  bvs[tid + 512] = bv[tid + 512];
  __syncthreads();

  int wave = tid >> 6;   // 0..7
  int lane = tid & 63;
  int row = blockIdx.x * 8 + wave;
  const f4* xr = reinterpret_cast<const f4*>(x + (size_t)row * Din);
  float acc0 = 0.f, acc1 = 0.f;
#pragma unroll
  for (int it = 0; it < 8; ++it) {
    f4 xa = xr[it * 128 + lane];
    f4 xb = xr[it * 128 + 64 + lane];
    f4 ba = bvs[it * 128 + lane];
    f4 bb = bvs[it * 128 + 64 + lane];
    acc0 += xa.x * ba.x + xa.y * ba.y + xa.z * ba.z + xa.w * ba.w;
    acc1 += xb.x * bb.x + xb.y * bb.y + xb.z * bb.z + xb.w * bb.w;
  }
  float acc = acc0 + acc1;
#pragma unroll
  for (int off = 32; off > 0; off >>= 1) acc += __shfl_down(acc, off, 64);
  __shared__ float tv[8];
  if (lane == 0) {
    t[row] = acc;
    tv[wave] = acc;
  }
  __syncthreads();
  if (tid == 0) {
    double s = 0.0, q = 0.0;
#pragma unroll
    for (int w = 0; w < 8; ++w) {
      double v = (double)tv[w];
      s += v;
      q += v * v;
    }
    partials[blockIdx.x] = make_double2(s, q);
  }
}

// ---------------- Kernel 3: finish = wave0-reduce + BN + leaky + write -------
// 512 blocks x 512 threads, 32 rows each; all 512 blocks co-resident (2/CU),
// so the redundant per-block stats reduction is paid once, in parallel.
// Wave 0 reduces all 2048 partials: 32 coalesced L2 load rounds + 6-round
// shfl tree -- NO __syncthreads inside, NO fences/atomics. Fixed order and
// identical inputs in every block -> bit-deterministic.
__global__ __launch_bounds__(512) void k_finish(
    const float* __restrict__ t, const double2* __restrict__ partials,
    const float* __restrict__ A, const float* __restrict__ gamma,
    const float* __restrict__ beta, float* __restrict__ out) {
  __shared__ double red[2];     // mean, var
  __shared__ float ss[Dout];
  __shared__ float bs[Dout];
  __shared__ float ts[32];
  int tid = threadIdx.x;
  if (tid >= 64 && tid < 96) ts[tid - 64] = t[blockIdx.x * 32 + (tid - 64)];
  if (tid < 64) {
    double ls = 0.0, lq = 0.0;
#pragma unroll
    for (int i = 0; i < NPART / 64; ++i) {   // 32 independent coalesced rounds
      double2 p = partials[tid + i * 64];
      ls += p.x;
      lq += p.y;
    }
#pragma unroll
    for (int off = 32; off > 0; off >>= 1) {
      ls += __shfl_down(ls, off, 64);
      lq += __shfl_down(lq, off, 64);
    }
    if (tid == 0) {
      double mean = ls / (double)B_;
      red[0] = mean;
      red[1] = lq / (double)B_ - mean * mean;  // biased, matches jnp.var
    }
  }
  __syncthreads();
  double mean = red[0];
  double var = red[1];
  if (tid < Dout) {
    float a = A[tid];
    float inv = rsqrtf((float)((double)a * (double)a * var) + BN_EPS);
    float sj = a * gamma[tid] * inv;
    ss[tid] = sj;
    bs[tid] = beta[tid] - (float)mean * sj;
  }
  __syncthreads();
#pragma unroll
  for (int j = 0; j < 4; ++j) {
    int idx = j * 512 + tid;     // 0..2047 = 32 rows x 64 f4
    int rin = idx >> 6;
    int c4 = idx & 63;
    int row = blockIdx.x * 32 + rin;
    float tvv = ts[rin];
    f4 sv = *reinterpret_cast<const f4*>(&ss[c4 * 4]);
    f4 bv = *reinterpret_cast<const f4*>(&bs[c4 * 4]);
    f4 o;
    o.x = tvv * sv.x + bv.x; o.x = (o.x >= 0.f) ? o.x : NEG_SLOPE * o.x;
    o.y = tvv * sv.y + bv.y; o.y = (o.y >= 0.f) ? o.y : NEG_SLOPE * o.y;
    o.z = tvv * sv.z + bv.z; o.z = (o.z >= 0.f) ? o.z : NEG_SLOPE * o.z;
    o.w = tvv * sv.w + bv.w; o.w = (o.w >= 0.f) ? o.w : NEG_SLOPE * o.w;
    reinterpret_cast<f4*>(out)[(size_t)row * (Dout / 4) + c4] = o;
  }
}

extern "C" void kernel_launch(void* const* d_in, const int* in_sizes, int n_in,
                              void* d_out, int out_size, void* d_ws, size_t ws_size,
                              hipStream_t stream) {
  const float* x      = (const float*)d_in[0];
  const float* alphas = (const float*)d_in[1];
  const float* cA     = (const float*)d_in[2];
  const float* cB     = (const float*)d_in[3];
  // d_in[4] = linear_bias: cancels exactly inside BatchNorm (out - mean).
  const float* gamma  = (const float*)d_in[5];
  const float* beta   = (const float*)d_in[6];
  float* out = (float*)d_out;
  float* ws  = (float*)d_ws;

  float*   Bv       = ws + WS_BV;
  float*   A        = ws + WS_A;
  float*   t        = ws + WS_T;
  double2* partials = reinterpret_cast<double2*>(ws + WS_PART);

  k_synth<<<1 + Din / 256, 256, 0, stream>>>(alphas, cA, cB, A, Bv);
  k_matvec<<<NPART, 512, 0, stream>>>(x, Bv, t, partials);
  k_finish<<<B_ / 32, 512, 0, stream>>>(t, partials, A, gamma, beta, out);
}